// Round 9
// baseline (367.045 us; speedup 1.0000x reference)
//
#include <hip/hip_runtime.h>

typedef unsigned short ushort_t;
typedef unsigned int   uint32;
typedef __attribute__((ext_vector_type(8)))  short short8;    // 8 x bf16 (4 VGPRs)
typedef __attribute__((ext_vector_type(4)))  float floatx4;
typedef __attribute__((ext_vector_type(16))) float floatx16;  // 32x32 MFMA accumulator
typedef __attribute__((ext_vector_type(4)))  int   intx4;     // NT-loadable int4
typedef __attribute__((ext_vector_type(4)))  float fltx4;     // NT-loadable float4

#define IN_F   4096
#define OUT_F  8192
#define M_TOT  512

__device__ __forceinline__ ushort_t f2bf(float f) {
    uint32 u = __builtin_bit_cast(uint32, f);
    u += 0x7FFFu + ((u >> 16) & 1u);    // RNE
    return (ushort_t)(u >> 16);
}
__device__ __forceinline__ uint32 pack2bf(float a, float b) {
    return (uint32)f2bf(a) | ((uint32)f2bf(b) << 16);
}

// ---------------------------------------------------------------------------
// Kernel 0: x fp32 -> bf16, MFMA-blocked layout XB[mt][kt][32][16]:
// ushort offset = ((mt*256 + kt)*32 + (m&31))*16 + (k&15),  mt=m>>5, kt=k>>4.
// Each 32x32x16 A-fragment is one contiguous 1 KB segment -> per-lane 16B
// fully-coalesced loads in the fused GEMM.
__global__ void cvt_x_kernel(const float* __restrict__ x, ushort_t* __restrict__ xb) {
    const int g  = blockIdx.x * 256 + threadIdx.x;   // 262144 threads total
    const int r  = g >> 9;                           // row 0..511
    const int k0 = (g & 511) * 8;                    // k octet
    float4 v0 = *(const float4*)(x + (size_t)r * IN_F + k0);
    float4 v1 = *(const float4*)(x + (size_t)r * IN_F + k0 + 4);
    short8 s;
    s[0] = (short)f2bf(v0.x); s[1] = (short)f2bf(v0.y);
    s[2] = (short)f2bf(v0.z); s[3] = (short)f2bf(v0.w);
    s[4] = (short)f2bf(v1.x); s[5] = (short)f2bf(v1.y);
    s[6] = (short)f2bf(v1.z); s[7] = (short)f2bf(v1.w);
    const int mt = r >> 5;
    const int kt = k0 >> 4;
    ushort_t* dst = xb + ((size_t)(mt * 256 + kt) * 32 + (r & 31)) * 16 + (k0 & 15);
    *(short8*)dst = s;
}

// ---------------------------------------------------------------------------
// Fused dequant + GEMM + scale, round-9: two-phase, BARRIER-FREE GEMM.
//
// R8 post-mortem: removing the in-loop waitcnt was null (109->108.4) -> the
// 32 block-wide sync points themselves (16-wave lockstep straggler
// propagation at 1 block/CU, no co-resident block to fill stalls) + the
// LDS-coupled dequant are the cost, not the drain.  All pipes <40% busy.
//
// New structure: phase 1 dequants the block's whole 32-col W strip (256 KB
// bf16) into GLOBAL workspace, MFMA-blocked exactly like XB; the strip is
// read back immediately by the SAME block -> L2/L3-hot, block-local sync
// only.  Phase 2 is a pure GEMM with ZERO barriers, ZERO LDS, ZERO sched
// fences: A and B both stream via per-lane-16B coalesced loads, 16
// independent waves, compiler free to software-pipeline.  B has 16x
// intra-block reuse (8 KB/iter << 32 KB L1) -> b-loads hit L1 after the
// first-toucher wave.  Kept: NT idx/LUT loads (R7, +15%).  Dropped: w-tile
// LDS machinery, setprio (no role diversity left), manual a-dbuf (compiler
// pipelines freely without fences).
__global__ __launch_bounds__(1024, 4)
void fused_kernel(const ushort_t* __restrict__ xb, const int* __restrict__ base_idx,
                  const int* __restrict__ fine_idx, const float* __restrict__ lut,
                  const float* __restrict__ scale, float* __restrict__ out,
                  ushort_t* __restrict__ wstrip)
{
    __shared__ ushort_t sh_lut[65536];        // 128 KB bf16 LUT (phase 1 only)

    const int tid  = threadIdx.x;
    const int nblk = blockIdx.x;              // col-block: cols [32*nblk, +32)

    // Stage LUT fp32 -> bf16 (NT: read once per block).
    for (int i = tid * 4; i < 65536; i += 4096) {
        fltx4 v = __builtin_nontemporal_load((const fltx4*)(lut + i));
        *(uint32*)&sh_lut[i]     = pack2bf(v.x, v.y);
        *(uint32*)&sh_lut[i + 2] = pack2bf(v.z, v.w);
    }

    // This block's strip: [kt 0..255][col 0..31][k16 0..15] bf16, 256 KB.
    ushort_t* strip = wstrip + (size_t)nblk * (32 * IN_F);

    // Phase-1 role: thread -> (col = tid>>5, lane l = tid&31).
    // k-groups: k0 = l*8 + s*256, s = 0..15 (idx loads coalesced: lane l at
    // byte offset l*32 -> contiguous 1 KB per wave-instruction).
    const int colr = tid >> 5;                // 0..31
    const int lnn  = tid & 31;
    const int*  bidx_row = base_idx + (size_t)(nblk * 32 + colr) * IN_F;
    const int*  fidx_row = fine_idx + (size_t)(nblk * 32 + colr) * IN_F;

    __syncthreads();                          // LUT ready

#pragma unroll 4
    for (int s = 0; s < 16; ++s) {
        const int k0 = lnn * 8 + s * 256;
        intx4 b0 = __builtin_nontemporal_load((const intx4*)(bidx_row + k0));
        intx4 b1 = __builtin_nontemporal_load((const intx4*)(bidx_row + k0 + 4));
        intx4 f0 = __builtin_nontemporal_load((const intx4*)(fidx_row + k0));
        intx4 f1 = __builtin_nontemporal_load((const intx4*)(fidx_row + k0 + 4));
        uint32 w0 = (uint32)sh_lut[(b0.x << 8) + f0.x]
                  | ((uint32)sh_lut[(b0.y << 8) + f0.y] << 16);
        uint32 w1 = (uint32)sh_lut[(b0.z << 8) + f0.z]
                  | ((uint32)sh_lut[(b0.w << 8) + f0.w] << 16);
        uint32 w2 = (uint32)sh_lut[(b1.x << 8) + f1.x]
                  | ((uint32)sh_lut[(b1.y << 8) + f1.y] << 16);
        uint32 w3 = (uint32)sh_lut[(b1.z << 8) + f1.z]
                  | ((uint32)sh_lut[(b1.w << 8) + f1.w] << 16);
        uint4 wv; wv.x = w0; wv.y = w1; wv.z = w2; wv.w = w3;
        // Strip address: kt = k0>>4, half = (k0>>3)&1.
        const int kt = k0 >> 4;
        *(uint4*)(strip + (size_t)(kt * 32 + colr) * 16 + ((k0 >> 3) & 1) * 8) = wv;
    }

    __syncthreads();   // strip visible (full vm+lgkm drain — wanted here)

    // ---- Phase 2: barrier-free GEMM ----
    const int lane = tid & 63;
    const int wave = tid >> 6;                // 0..15 = m-tile index
    const int l31  = lane & 31;
    const int lhi  = lane >> 5;

    floatx16 acc = {0.f,0.f,0.f,0.f,0.f,0.f,0.f,0.f,0.f,0.f,0.f,0.f,0.f,0.f,0.f,0.f};

    // Blocked bases: tile kt = 512 ushorts; lane slot l31*16 + lhi*8 (16 B).
    const ushort_t* abase = xb    + (size_t)wave * 256 * 512 + l31 * 16 + lhi * 8;
    const ushort_t* bbase = strip + l31 * 16 + lhi * 8;

#pragma unroll 2
    for (int t = 0; t < 32; ++t) {            // 8 kt per iter (BK=128)
        short8 a0 = *(const short8*)(abase + (size_t)(t * 8 + 0) * 512);
        short8 a1 = *(const short8*)(abase + (size_t)(t * 8 + 1) * 512);
        short8 a2 = *(const short8*)(abase + (size_t)(t * 8 + 2) * 512);
        short8 a3 = *(const short8*)(abase + (size_t)(t * 8 + 3) * 512);
        short8 a4 = *(const short8*)(abase + (size_t)(t * 8 + 4) * 512);
        short8 a5 = *(const short8*)(abase + (size_t)(t * 8 + 5) * 512);
        short8 a6 = *(const short8*)(abase + (size_t)(t * 8 + 6) * 512);
        short8 a7 = *(const short8*)(abase + (size_t)(t * 8 + 7) * 512);
        short8 b0 = *(const short8*)(bbase + (size_t)(t * 8 + 0) * 512);
        short8 b1 = *(const short8*)(bbase + (size_t)(t * 8 + 1) * 512);
        short8 b2 = *(const short8*)(bbase + (size_t)(t * 8 + 2) * 512);
        short8 b3 = *(const short8*)(bbase + (size_t)(t * 8 + 3) * 512);
        short8 b4 = *(const short8*)(bbase + (size_t)(t * 8 + 4) * 512);
        short8 b5 = *(const short8*)(bbase + (size_t)(t * 8 + 5) * 512);
        short8 b6 = *(const short8*)(bbase + (size_t)(t * 8 + 6) * 512);
        short8 b7 = *(const short8*)(bbase + (size_t)(t * 8 + 7) * 512);
        acc = __builtin_amdgcn_mfma_f32_32x32x16_bf16(a0, b0, acc, 0, 0, 0);
        acc = __builtin_amdgcn_mfma_f32_32x32x16_bf16(a1, b1, acc, 0, 0, 0);
        acc = __builtin_amdgcn_mfma_f32_32x32x16_bf16(a2, b2, acc, 0, 0, 0);
        acc = __builtin_amdgcn_mfma_f32_32x32x16_bf16(a3, b3, acc, 0, 0, 0);
        acc = __builtin_amdgcn_mfma_f32_32x32x16_bf16(a4, b4, acc, 0, 0, 0);
        acc = __builtin_amdgcn_mfma_f32_32x32x16_bf16(a5, b5, acc, 0, 0, 0);
        acc = __builtin_amdgcn_mfma_f32_32x32x16_bf16(a6, b6, acc, 0, 0, 0);
        acc = __builtin_amdgcn_mfma_f32_32x32x16_bf16(a7, b7, acc, 0, 0, 0);
    }

    // Epilogue: out[row][col] = acc * scale[col]  (32x32 C/D mapping:
    // col=l31, row=(reg&3)+8*(reg>>2)+4*lhi — verified in earlier rounds).
    const float sc = scale[nblk * 32 + l31];
    float* op = out + (size_t)(nblk * 32 + l31);
    const int rbase = wave * 32 + 4 * lhi;
#pragma unroll
    for (int reg = 0; reg < 16; ++reg) {
        const int row = rbase + (reg & 3) + 8 * (reg >> 2);
        op[(size_t)row * OUT_F] = acc[reg] * sc;
    }
}

// ---------------------------------------------------------------------------
// Fallback: fused kernel for tiny workspace (x read as fp32).
#define NB  32
#define FBK 128
#define WS  136
#define NITER (IN_F / FBK)
__global__ __launch_bounds__(1024, 4)
void ghost_kernel(const float* __restrict__ xf,
                  const int* __restrict__ base_idx, const int* __restrict__ fine_idx,
                  const float* __restrict__ scale, const float* __restrict__ lut,
                  float* __restrict__ out)
{
    __shared__ ushort_t sh_lut[65536];
    __shared__ ushort_t sh_w[2][NB * WS];
    const int tid = threadIdx.x;
    const int n0  = blockIdx.x * NB;
    for (int i = tid * 4; i < 65536; i += 1024 * 4) {
        float4 v = *(const float4*)(lut + i);
        sh_lut[i + 0] = f2bf(v.x); sh_lut[i + 1] = f2bf(v.y);
        sh_lut[i + 2] = f2bf(v.z); sh_lut[i + 3] = f2bf(v.w);
    }
    const int sn  = tid >> 5;
    const int skq = (tid & 31) * 4;
    const int* bp = base_idx + (size_t)(n0 + sn) * IN_F + skq;
    const int* fp = fine_idx + (size_t)(n0 + sn) * IN_F + skq;
    __syncthreads();
    int4 pb = *(const int4*)(bp);
    int4 pf = *(const int4*)(fp);
    {
        uint32 w0 = (uint32)sh_lut[(pb.x << 8) + pf.x] | ((uint32)sh_lut[(pb.y << 8) + pf.y] << 16);
        uint32 w1 = (uint32)sh_lut[(pb.z << 8) + pf.z] | ((uint32)sh_lut[(pb.w << 8) + pf.w] << 16);
        uint2 wv; wv.x = w0; wv.y = w1;
        *(uint2*)&sh_w[0][sn * WS + skq] = wv;
    }
    pb = *(const int4*)(bp + FBK);
    pf = *(const int4*)(fp + FBK);
    __syncthreads();
    const int lane = tid & 63;
    const int wave = tid >> 6;
    const int l16  = lane & 15;
    const int quad = lane >> 4;
    floatx4 acc[2][2];
    const floatx4 zero = {0.f, 0.f, 0.f, 0.f};
    acc[0][0] = zero; acc[0][1] = zero; acc[1][0] = zero; acc[1][1] = zero;
    const int mrow = wave * 32 + l16;
    const float* xrowf = xf + (size_t)mrow * IN_F + quad * 8;
    for (int t = 0; t < NITER; ++t) {
        const int k0 = t * FBK;
        {
            uint32 w0 = (uint32)sh_lut[(pb.x << 8) + pf.x] | ((uint32)sh_lut[(pb.y << 8) + pf.y] << 16);
            uint32 w1 = (uint32)sh_lut[(pb.z << 8) + pf.z] | ((uint32)sh_lut[(pb.w << 8) + pf.w] << 16);
            uint2 wv; wv.x = w0; wv.y = w1;
            *(uint2*)&sh_w[(t + 1) & 1][sn * WS + skq] = wv;
        }
        {
            const int kk = (t + 2 < NITER ? t + 2 : NITER - 1) * FBK;
            pb = *(const int4*)(bp + kk);
            pf = *(const int4*)(fp + kk);
        }
        const ushort_t* wb = sh_w[t & 1];
#pragma unroll
        for (int ks = 0; ks < 4; ++ks) {
            const int kk = k0 + ks * 32;
            short8 b0 = *(const short8*)&wb[l16        * WS + ks * 32 + quad * 8];
            short8 b1 = *(const short8*)&wb[(16 + l16) * WS + ks * 32 + quad * 8];
            short8 a0, a1;
            const float* p0 = xrowf + kk;
            const float* p1 = xrowf + (size_t)16 * IN_F + kk;
            float4 u0 = *(const float4*)p0, u1 = *(const float4*)(p0 + 4);
            float4 v0 = *(const float4*)p1, v1 = *(const float4*)(p1 + 4);
            a0[0] = (short)f2bf(u0.x); a0[1] = (short)f2bf(u0.y);
            a0[2] = (short)f2bf(u0.z); a0[3] = (short)f2bf(u0.w);
            a0[4] = (short)f2bf(u1.x); a0[5] = (short)f2bf(u1.y);
            a0[6] = (short)f2bf(u1.z); a0[7] = (short)f2bf(u1.w);
            a1[0] = (short)f2bf(v0.x); a1[1] = (short)f2bf(v0.y);
            a1[2] = (short)f2bf(v0.z); a1[3] = (short)f2bf(v0.w);
            a1[4] = (short)f2bf(v1.x); a1[5] = (short)f2bf(v1.y);
            a1[6] = (short)f2bf(v1.z); a1[7] = (short)f2bf(v1.w);
            acc[0][0] = __builtin_amdgcn_mfma_f32_16x16x32_bf16(a0, b0, acc[0][0], 0, 0, 0);
            acc[0][1] = __builtin_amdgcn_mfma_f32_16x16x32_bf16(a0, b1, acc[0][1], 0, 0, 0);
            acc[1][0] = __builtin_amdgcn_mfma_f32_16x16x32_bf16(a1, b0, acc[1][0], 0, 0, 0);
            acc[1][1] = __builtin_amdgcn_mfma_f32_16x16x32_bf16(a1, b1, acc[1][1], 0, 0, 0);
        }
        __syncthreads();
    }
#pragma unroll
    for (int nf = 0; nf < 2; ++nf) {
        const int col = n0 + nf * 16 + l16;
        const float sc = scale[col];
#pragma unroll
        for (int f = 0; f < 2; ++f) {
            const int r0 = wave * 32 + f * 16 + quad * 4;
#pragma unroll
            for (int r = 0; r < 4; ++r) {
                out[(size_t)(r0 + r) * OUT_F + col] = acc[f][nf][r] * sc;
            }
        }
    }
}

// ---------------------------------------------------------------------------
extern "C" void kernel_launch(void* const* d_in, const int* in_sizes, int n_in,
                              void* d_out, int out_size, void* d_ws, size_t ws_size,
                              hipStream_t stream) {
    const float* x      = (const float*)d_in[0];
    const int*   bidx   = (const int*)d_in[1];
    const int*   fidx   = (const int*)d_in[2];
    const float* scale  = (const float*)d_in[3];
    const float* lut    = (const float*)d_in[4];
    float*       out    = (float*)d_out;

    const size_t xb_bytes = (size_t)M_TOT * IN_F * sizeof(ushort_t);   // 4 MB
    const size_t wq_bytes = (size_t)OUT_F * IN_F * sizeof(ushort_t);   // 64 MB

    if (ws_size >= xb_bytes + wq_bytes) {
        ushort_t* xbuf = (ushort_t*)d_ws;
        ushort_t* wbuf = (ushort_t*)((char*)d_ws + xb_bytes);
        cvt_x_kernel<<<1024, 256, 0, stream>>>(x, xbuf);
        fused_kernel<<<256, 1024, 0, stream>>>(xbuf, bidx, fidx, lut, scale, out, wbuf);
    } else {
        ghost_kernel<<<OUT_F / NB, 1024, 0, stream>>>(x, bidx, fidx, scale, lut, out);
    }
}

// Round 10
// 326.851 us; speedup vs baseline: 1.1230x; 1.1230x over previous
//
#include <hip/hip_runtime.h>

typedef unsigned short ushort_t;
typedef unsigned int   uint32;
typedef __attribute__((ext_vector_type(8)))  short short8;    // 8 x bf16 (4 VGPRs)
typedef __attribute__((ext_vector_type(4)))  float floatx4;
typedef __attribute__((ext_vector_type(16))) float floatx16;  // 32x32 MFMA accumulator
typedef __attribute__((ext_vector_type(4)))  int   intx4;     // NT-loadable int4
typedef __attribute__((ext_vector_type(4)))  float fltx4;     // NT-loadable float4

#define IN_F   4096
#define OUT_F  8192
#define M_TOT  512

__device__ __forceinline__ ushort_t f2bf(float f) {
    uint32 u = __builtin_bit_cast(uint32, f);
    u += 0x7FFFu + ((u >> 16) & 1u);    // RNE
    return (ushort_t)(u >> 16);
}
__device__ __forceinline__ uint32 pack2bf(float a, float b) {
    return (uint32)f2bf(a) | ((uint32)f2bf(b) << 16);
}

// ---------------------------------------------------------------------------
// Kernel 0: x fp32 -> bf16, MFMA-blocked layout XB[mt][kt][32][16]:
// ushort offset = ((mt*256 + kt)*32 + (m&31))*16 + (k&15),  mt=m>>5, kt=k>>4.
// Each 32x32x16 A-fragment is one contiguous 1 KB segment -> per-lane 16B
// fully-coalesced loads in the fused GEMM.
__global__ void cvt_x_kernel(const float* __restrict__ x, ushort_t* __restrict__ xb) {
    const int g  = blockIdx.x * 256 + threadIdx.x;   // 262144 threads total
    const int r  = g >> 9;                           // row 0..511
    const int k0 = (g & 511) * 8;                    // k octet
    float4 v0 = *(const float4*)(x + (size_t)r * IN_F + k0);
    float4 v1 = *(const float4*)(x + (size_t)r * IN_F + k0 + 4);
    short8 s;
    s[0] = (short)f2bf(v0.x); s[1] = (short)f2bf(v0.y);
    s[2] = (short)f2bf(v0.z); s[3] = (short)f2bf(v0.w);
    s[4] = (short)f2bf(v1.x); s[5] = (short)f2bf(v1.y);
    s[6] = (short)f2bf(v1.z); s[7] = (short)f2bf(v1.w);
    const int mt = r >> 5;
    const int kt = k0 >> 4;
    ushort_t* dst = xb + ((size_t)(mt * 256 + kt) * 32 + (r & 31)) * 16 + (k0 & 15);
    *(short8*)dst = s;
}

// ---------------------------------------------------------------------------
// Fused dequant + GEMM + scale, round-10: 8 waves x 2 m-tiles.
//
// R9 (strip-to-global) REGRESSED (108->160us; WRITE 22->84MB, FETCH
// 151->215MB — the strip roundtrip went to HBM, not L2).  Reverted to the
// R8 skeleton.  R8's remaining cost model: LDS pipe ~2.5k cyc/iter, of
// which ~1.5k is b-frag reads — 16 waves each re-read the full 8KB B-tile
// every iter (128KB LDS reads/iter).  Fix: 512 threads / 8 waves, each
// owning TWO m-tiles (64 rows): every b-frag is read from LDS once and
// feeds TWO MFMAs -> b-read traffic halves, per-wave MFMA ILP doubles,
// barrier straggler width halves (8 waves).  Kept (all verified R5-R8):
// tri-buffered sh_w + ZERO in-loop waitcnt, NT idx/LUT loads, dequant
// after MFMA cluster, setprio around MFMAs, reg-dbuf a-frags one iter
// ahead, BK=128 / 32 iters.
__global__ __launch_bounds__(512, 2)
void fused_kernel(const ushort_t* __restrict__ xb, const int* __restrict__ base_idx,
                  const int* __restrict__ fine_idx, const float* __restrict__ lut,
                  const float* __restrict__ scale, float* __restrict__ out)
{
    __shared__ ushort_t sh_lut[65536];        // 128 KB bf16 LUT
    __shared__ ushort_t sh_w[3][32 * 128];    // 3 x 8 KB w-tiles (BK=128)

    const int tid  = threadIdx.x;
    const int nblk = blockIdx.x;              // col-block: cols [32*nblk, +32)

    // Stage LUT fp32 -> bf16 (NT: read once per block).  512 thr -> 32 iters.
    for (int i = tid * 4; i < 65536; i += 2048) {
        fltx4 v = __builtin_nontemporal_load((const fltx4*)(lut + i));
        *(uint32*)&sh_lut[i]     = pack2bf(v.x, v.y);
        *(uint32*)&sh_lut[i + 2] = pack2bf(v.z, v.w);
    }

    // Dequant role: thread -> (col = tid>>4, k-octet = (tid&15)*8).
    // 512 thr x 8 elems = 4096 = one 32x128 tile.  One uint4 (16B) write.
    const int colr = tid >> 4;                // 0..31
    const int koct = (tid & 15) * 8;          // 0,8,..,120
    const intx4* bp = (const intx4*)(base_idx + (size_t)(nblk * 32 + colr) * IN_F + koct);
    const intx4* fp = (const intx4*)(fine_idx + (size_t)(nblk * 32 + colr) * IN_F + koct);
    // tile t lives at bp[t*32] (+1 for the second int4)

    // Swizzled write offset: chunk c = tid&15 -> slot c ^ (colr&7) (low 3
    // bits), one full 16B chunk per thread.
    const int woff = colr * 128 + (((tid & 15) ^ (colr & 7)) << 3);

    const int lane = tid & 63;
    const int wave = tid >> 6;                // 0..7; owns m-tiles 2w, 2w+1
    const int l31  = lane & 31;
    const int lhi  = lane >> 5;
    const int rx8  = l31 & 7;                 // read-side swizzle key

    // Blocked A bases: tile kt = 512 ushorts; m-tile stride = 256*512.
    const ushort_t* abase = xb + (size_t)(wave * 2) * 256 * 512 + l31 * 16 + lhi * 8;
    // second m-tile at abase + 131072

    // Prologue index loads (NT, single-use stream).
    intx4 i0bA = __builtin_nontemporal_load(bp);            // tile 0
    intx4 i0bB = __builtin_nontemporal_load(bp + 1);
    intx4 i0fA = __builtin_nontemporal_load(fp);
    intx4 i0fB = __builtin_nontemporal_load(fp + 1);
    intx4 i1bA = __builtin_nontemporal_load(bp + 32);       // tile 1
    intx4 i1bB = __builtin_nontemporal_load(bp + 33);
    intx4 i1fA = __builtin_nontemporal_load(fp + 32);
    intx4 i1fB = __builtin_nontemporal_load(fp + 33);
    intx4 IbA  = __builtin_nontemporal_load(bp + 64);       // tile 2
    intx4 IbB  = __builtin_nontemporal_load(bp + 65);
    intx4 IfA  = __builtin_nontemporal_load(fp + 64);
    intx4 IfB  = __builtin_nontemporal_load(fp + 65);
    intx4 NbA  = __builtin_nontemporal_load(bp + 96);       // tile 3
    intx4 NbB  = __builtin_nontemporal_load(bp + 97);
    intx4 NfA  = __builtin_nontemporal_load(fp + 96);
    intx4 NfB  = __builtin_nontemporal_load(fp + 97);

    // Preload a-frags for t=0 (bank A), both m-tiles.
    short8 aA0[8], aA1[8], aB0[8], aB1[8];
#pragma unroll
    for (int i = 0; i < 8; ++i) {
        aA0[i] = *(const short8*)(abase + (size_t)i * 512);
        aA1[i] = *(const short8*)(abase + 131072 + (size_t)i * 512);
    }

    // LUT ready (full drain, once).
    asm volatile("s_waitcnt lgkmcnt(0)" ::: "memory");
    __builtin_amdgcn_sched_barrier(0);
    __builtin_amdgcn_s_barrier();

#define DEQ8(BA, BB, FA, FB, DST)                                              \
    {                                                                          \
        uint32 w0 = (uint32)sh_lut[((BA).x << 8) + (FA).x]                     \
                  | ((uint32)sh_lut[((BA).y << 8) + (FA).y] << 16);            \
        uint32 w1 = (uint32)sh_lut[((BA).z << 8) + (FA).z]                     \
                  | ((uint32)sh_lut[((BA).w << 8) + (FA).w] << 16);            \
        uint32 w2 = (uint32)sh_lut[((BB).x << 8) + (FB).x]                     \
                  | ((uint32)sh_lut[((BB).y << 8) + (FB).y] << 16);            \
        uint32 w3 = (uint32)sh_lut[((BB).z << 8) + (FB).z]                     \
                  | ((uint32)sh_lut[((BB).w << 8) + (FB).w] << 16);            \
        uint4 wv; wv.x = w0; wv.y = w1; wv.z = w2; wv.w = w3;                  \
        *(uint4*)(DST) = wv;                                                   \
    }

    DEQ8(i0bA, i0bB, i0fA, i0fB, &sh_w[0][woff])   // tile 0 -> buf0
    DEQ8(i1bA, i1bB, i1fA, i1fB, &sh_w[1][woff])   // tile 1 -> buf1

    // bufs 0,1 visible (full drain, once).
    asm volatile("s_waitcnt lgkmcnt(0)" ::: "memory");
    __builtin_amdgcn_sched_barrier(0);
    __builtin_amdgcn_s_barrier();

    const floatx16 z16 = {0.f,0.f,0.f,0.f,0.f,0.f,0.f,0.f,0.f,0.f,0.f,0.f,0.f,0.f,0.f,0.f};
    floatx16 acc0 = z16, acc1 = z16;

    // Body at iter T: (1) NT idx loads tile T+4 (temps), (2) a-prefetch T+1
    // into bank AY (both m-tiles), (3) 8 b-reads x 2 MFMAs on buf[CUR]
    // (setprio-wrapped), (4) dequant tile T+2 into buf[WD], rotate pipeline,
    // (5) raw barrier, NO waitcnt.  All indices compile-time (6-body unroll).
#define GBODY(K, AX0, AX1, AY0, AY1, CUR, WD)                                  \
    {                                                                          \
        const int T = t + (K);                                                 \
        intx4 PbA = {0,0,0,0}, PbB = {0,0,0,0}, PfA = {0,0,0,0}, PfB = {0,0,0,0}; \
        if (T + 4 < 32) {                                                      \
            PbA = __builtin_nontemporal_load(bp + (T + 4) * 32);               \
            PbB = __builtin_nontemporal_load(bp + (T + 4) * 32 + 1);           \
            PfA = __builtin_nontemporal_load(fp + (T + 4) * 32);               \
            PfB = __builtin_nontemporal_load(fp + (T + 4) * 32 + 1);           \
        }                                                                      \
        if (T + 1 < 32) {                                                      \
            _Pragma("unroll")                                                  \
            for (int i = 0; i < 8; ++i) {                                      \
                AY0[i] = *(const short8*)(abase + (size_t)((T + 1) * 8 + i) * 512); \
                AY1[i] = *(const short8*)(abase + 131072 + (size_t)((T + 1) * 8 + i) * 512); \
            }                                                                  \
        }                                                                      \
        const ushort_t* wb = sh_w[CUR];                                        \
        __builtin_amdgcn_s_setprio(1);                                         \
        _Pragma("unroll")                                                      \
        for (int ks = 0; ks < 8; ++ks) {                                       \
            short8 bfr = *(const short8*)&wb[l31 * 128 + (((2 * ks + lhi) ^ rx8) << 3)]; \
            acc0 = __builtin_amdgcn_mfma_f32_32x32x16_bf16(AX0[ks], bfr, acc0, 0, 0, 0); \
            acc1 = __builtin_amdgcn_mfma_f32_32x32x16_bf16(AX1[ks], bfr, acc1, 0, 0, 0); \
        }                                                                      \
        __builtin_amdgcn_s_setprio(0);                                         \
        if (T + 2 < 32) {                                                      \
            DEQ8(IbA, IbB, IfA, IfB, &sh_w[WD][woff])                          \
            IbA = NbA; IbB = NbB; IfA = NfA; IfB = NfB;                        \
            NbA = PbA; NbB = PbB; NfA = PfA; NfB = PfB;                        \
        }                                                                      \
        __builtin_amdgcn_sched_barrier(0);                                     \
        __builtin_amdgcn_s_barrier();                                          \
    }

    int t = 0;
    for (; t < 30; t += 6) {
        GBODY(0, aA0, aA1, aB0, aB1, 0, 2)
        GBODY(1, aB0, aB1, aA0, aA1, 1, 0)
        GBODY(2, aA0, aA1, aB0, aB1, 2, 1)
        GBODY(3, aB0, aB1, aA0, aA1, 0, 2)
        GBODY(4, aA0, aA1, aB0, aB1, 1, 0)
        GBODY(5, aB0, aB1, aA0, aA1, 2, 1)
    }
    // t == 30 tail (T=30 reads buf0 w/ bank A; T=31 reads buf1 w/ bank B).
    GBODY(0, aA0, aA1, aB0, aB1, 0, 2)
    GBODY(1, aB0, aB1, aA0, aA1, 1, 0)
#undef GBODY
#undef DEQ8

    // Epilogue: out[row][col] = acc * scale[col]  (32x32 C/D mapping:
    // col=l31, row=(reg&3)+8*(reg>>2)+4*lhi — verified in earlier rounds).
    const float sc = scale[nblk * 32 + l31];
    float* op = out + (size_t)(nblk * 32 + l31);
#pragma unroll
    for (int mt = 0; mt < 2; ++mt) {
        const floatx16 a = mt ? acc1 : acc0;
        const int rbase = (wave * 2 + mt) * 32 + 4 * lhi;
#pragma unroll
        for (int reg = 0; reg < 16; ++reg) {
            const int row = rbase + (reg & 3) + 8 * (reg >> 2);
            op[(size_t)row * OUT_F] = a[reg] * sc;
        }
    }
}

// ---------------------------------------------------------------------------
// Fallback: fused kernel for tiny workspace (x read as fp32).
#define NB  32
#define FBK 128
#define WS  136
#define NITER (IN_F / FBK)
__global__ __launch_bounds__(1024, 4)
void ghost_kernel(const float* __restrict__ xf,
                  const int* __restrict__ base_idx, const int* __restrict__ fine_idx,
                  const float* __restrict__ scale, const float* __restrict__ lut,
                  float* __restrict__ out)
{
    __shared__ ushort_t sh_lut[65536];
    __shared__ ushort_t sh_w[2][NB * WS];
    const int tid = threadIdx.x;
    const int n0  = blockIdx.x * NB;
    for (int i = tid * 4; i < 65536; i += 1024 * 4) {
        float4 v = *(const float4*)(lut + i);
        sh_lut[i + 0] = f2bf(v.x); sh_lut[i + 1] = f2bf(v.y);
        sh_lut[i + 2] = f2bf(v.z); sh_lut[i + 3] = f2bf(v.w);
    }
    const int sn  = tid >> 5;
    const int skq = (tid & 31) * 4;
    const int* bp = base_idx + (size_t)(n0 + sn) * IN_F + skq;
    const int* fp = fine_idx + (size_t)(n0 + sn) * IN_F + skq;
    __syncthreads();
    int4 pb = *(const int4*)(bp);
    int4 pf = *(const int4*)(fp);
    {
        uint32 w0 = (uint32)sh_lut[(pb.x << 8) + pf.x] | ((uint32)sh_lut[(pb.y << 8) + pf.y] << 16);
        uint32 w1 = (uint32)sh_lut[(pb.z << 8) + pf.z] | ((uint32)sh_lut[(pb.w << 8) + pf.w] << 16);
        uint2 wv; wv.x = w0; wv.y = w1;
        *(uint2*)&sh_w[0][sn * WS + skq] = wv;
    }
    pb = *(const int4*)(bp + FBK);
    pf = *(const int4*)(fp + FBK);
    __syncthreads();
    const int lane = tid & 63;
    const int wave = tid >> 6;
    const int l16  = lane & 15;
    const int quad = lane >> 4;
    floatx4 acc[2][2];
    const floatx4 zero = {0.f, 0.f, 0.f, 0.f};
    acc[0][0] = zero; acc[0][1] = zero; acc[1][0] = zero; acc[1][1] = zero;
    const int mrow = wave * 32 + l16;
    const float* xrowf = xf + (size_t)mrow * IN_F + quad * 8;
    for (int t = 0; t < NITER; ++t) {
        const int k0 = t * FBK;
        {
            uint32 w0 = (uint32)sh_lut[(pb.x << 8) + pf.x] | ((uint32)sh_lut[(pb.y << 8) + pf.y] << 16);
            uint32 w1 = (uint32)sh_lut[(pb.z << 8) + pf.z] | ((uint32)sh_lut[(pb.w << 8) + pf.w] << 16);
            uint2 wv; wv.x = w0; wv.y = w1;
            *(uint2*)&sh_w[(t + 1) & 1][sn * WS + skq] = wv;
        }
        {
            const int kk = (t + 2 < NITER ? t + 2 : NITER - 1) * FBK;
            pb = *(const int4*)(bp + kk);
            pf = *(const int4*)(fp + kk);
        }
        const ushort_t* wb = sh_w[t & 1];
#pragma unroll
        for (int ks = 0; ks < 4; ++ks) {
            const int kk = k0 + ks * 32;
            short8 b0 = *(const short8*)&wb[l16        * WS + ks * 32 + quad * 8];
            short8 b1 = *(const short8*)&wb[(16 + l16) * WS + ks * 32 + quad * 8];
            short8 a0, a1;
            const float* p0 = xrowf + kk;
            const float* p1 = xrowf + (size_t)16 * IN_F + kk;
            float4 u0 = *(const float4*)p0, u1 = *(const float4*)(p0 + 4);
            float4 v0 = *(const float4*)p1, v1 = *(const float4*)(p1 + 4);
            a0[0] = (short)f2bf(u0.x); a0[1] = (short)f2bf(u0.y);
            a0[2] = (short)f2bf(u0.z); a0[3] = (short)f2bf(u0.w);
            a0[4] = (short)f2bf(u1.x); a0[5] = (short)f2bf(u1.y);
            a0[6] = (short)f2bf(u1.z); a0[7] = (short)f2bf(u1.w);
            a1[0] = (short)f2bf(v0.x); a1[1] = (short)f2bf(v0.y);
            a1[2] = (short)f2bf(v0.z); a1[3] = (short)f2bf(v0.w);
            a1[4] = (short)f2bf(v1.x); a1[5] = (short)f2bf(v1.y);
            a1[6] = (short)f2bf(v1.z); a1[7] = (short)f2bf(v1.w);
            acc[0][0] = __builtin_amdgcn_mfma_f32_16x16x32_bf16(a0, b0, acc[0][0], 0, 0, 0);
            acc[0][1] = __builtin_amdgcn_mfma_f32_16x16x32_bf16(a0, b1, acc[0][1], 0, 0, 0);
            acc[1][0] = __builtin_amdgcn_mfma_f32_16x16x32_bf16(a1, b0, acc[1][0], 0, 0, 0);
            acc[1][1] = __builtin_amdgcn_mfma_f32_16x16x32_bf16(a1, b1, acc[1][1], 0, 0, 0);
        }
        __syncthreads();
    }
#pragma unroll
    for (int nf = 0; nf < 2; ++nf) {
        const int col = n0 + nf * 16 + l16;
        const float sc = scale[col];
#pragma unroll
        for (int f = 0; f < 2; ++f) {
            const int r0 = wave * 32 + f * 16 + quad * 4;
#pragma unroll
            for (int r = 0; r < 4; ++r) {
                out[(size_t)(r0 + r) * OUT_F + col] = acc[f][nf][r] * sc;
            }
        }
    }
}

// ---------------------------------------------------------------------------
extern "C" void kernel_launch(void* const* d_in, const int* in_sizes, int n_in,
                              void* d_out, int out_size, void* d_ws, size_t ws_size,
                              hipStream_t stream) {
    const float* x      = (const float*)d_in[0];
    const int*   bidx   = (const int*)d_in[1];
    const int*   fidx   = (const int*)d_in[2];
    const float* scale  = (const float*)d_in[3];
    const float* lut    = (const float*)d_in[4];
    float*       out    = (float*)d_out;

    const size_t xb_bytes = (size_t)M_TOT * IN_F * sizeof(ushort_t);   // 4 MB

    if (ws_size >= xb_bytes) {
        ushort_t* xbuf = (ushort_t*)d_ws;
        cvt_x_kernel<<<1024, 256, 0, stream>>>(x, xbuf);
        fused_kernel<<<256, 512, 0, stream>>>(xbuf, bidx, fidx, lut, scale, out);
    } else {
        ghost_kernel<<<OUT_F / NB, 1024, 0, stream>>>(x, bidx, fidx, scale, lut, out);
    }
}